// Round 9
// baseline (199.077 us; speedup 1.0000x reference)
//
#include <hip/hip_runtime.h>

#define NTOT 100000

typedef float f32x4 __attribute__((ext_vector_type(4)));
typedef short s16x8 __attribute__((ext_vector_type(8)));
typedef short s16x4 __attribute__((ext_vector_type(4)));
typedef unsigned int u32x2 __attribute__((ext_vector_type(2)));
typedef unsigned short u16;
typedef unsigned int u32;

__device__ __forceinline__ u16 bfbits(float f) {
    return __builtin_bit_cast(u16, (__bf16)f);
}
__device__ __forceinline__ u32 packbf2(float a, float b) {
    return (u32)bfbits(a) | ((u32)bfbits(b) << 16);
}
__device__ __forceinline__ float bf2f(u16 u) {
    u32 v = ((u32)u) << 16;
    return __builtin_bit_cast(float, v);
}
__device__ __forceinline__ s16x8 cvt8(const float* __restrict__ p) {
    f32x4 lo = *(const f32x4*)p;
    f32x4 hi = *(const f32x4*)(p + 4);
    s16x8 r;
#pragma unroll
    for (int e = 0; e < 4; ++e) r[e] = (short)bfbits(lo[e]);
#pragma unroll
    for (int e = 0; e < 4; ++e) r[4 + e] = (short)bfbits(hi[e]);
    return r;
}
// async global->LDS, 16B per lane; LDS dest = wave-uniform base + lane*16
__device__ __forceinline__ void gload16(const void* g, void* lds) {
    __builtin_amdgcn_global_load_lds(
        (const __attribute__((address_space(1))) u32*)g,
        (__attribute__((address_space(3))) u32*)lds, 16, 0, 0);
}

// ds_read_b64_tr_b16 (HW-verified r7): per-lane addr = subtile_base + l15*8
// yields lane k, elem j = subtile[row j][col k] of a [4][16]-bf16 tile.
__device__ __forceinline__ s16x4 trread(unsigned a) {
    s16x4 d;
    asm volatile("ds_read_b64_tr_b16 %0, %1" : "=v"(d) : "v"(a));
    return d;
}
__device__ __forceinline__ s16x4 trread2k(unsigned a) {
    s16x4 d;
    asm volatile("ds_read_b64_tr_b16 %0, %1 offset:2048" : "=v"(d) : "v"(a));
    return d;
}
struct S2 { s16x4 lo, hi; };
__device__ __forceinline__ s16x8 cat44(s16x4 lo, s16x4 hi) {
    S2 s{lo, hi};
    return __builtin_bit_cast(s16x8, s);
}
// rule 18: lgkmcnt(0) + sched_barrier after inline-asm ds reads
#define LGKM0_FENCE()                                         \
    do {                                                      \
        asm volatile("s_waitcnt lgkmcnt(0)" ::: "memory");    \
        __builtin_amdgcn_sched_barrier(0);                    \
    } while (0)

// ---------------- kernel 1: Cayley weights -------------------------------
__global__ void k_weights(const float* __restrict__ ev, const float* __restrict__ hp,
                          const float* __restrict__ ap, float* __restrict__ br,
                          float* __restrict__ bi) {
    int k = threadIdx.x;
    float h = hp[0], alpha = ap[0];
    float t = h * (ev[k] - alpha);
    float inv = 1.0f / (t * t + 1.0f);
    float b_re = (t * t - 1.0f) * inv;
    float b_im = -2.0f * t * inv;
    float cr = b_re, ci = b_im;
    br[k] = cr; bi[k] = ci;
#pragma unroll
    for (int j = 1; j < 8; ++j) {
        float nr = cr * b_re - ci * b_im;
        float ni = cr * b_im + ci * b_re;
        cr = nr; ci = ni;
        br[j * 256 + k] = cr;
        bi[j * 256 + k] = ci;
    }
}

// ---------------- kernel 2: P_partial(bf16) = E^T @ x --------------------
// (unchanged from r8 -- passing at ~90 us; frozen this round)
__global__ __launch_bounds__(1024, 4) void k_gemm1(
    const float* __restrict__ E, const float* __restrict__ X,
    u16* __restrict__ Pp, int NB) {
    __shared__ alignas(16) u16 Et[2][8192];   // 2 x 16 KB subtiled
    __shared__ alignas(16) u16 Xt[2][8192];   // 2 x 16 KB

    int chunk = blockIdx.x;
    int nStart = chunk * NB;
    int nEnd = min(nStart + NB, NTOT);
    if (nEnd <= nStart) return;

    int t = threadIdx.x, lane = t & 63, w = t >> 6;
    int wk = w & 3, wi = w >> 2;           // compute roles: 64k x 64i / wave
    int l15 = lane & 15, lhi = lane >> 4;
    int rg = w >> 1, qh = w & 1;           // staging roles: row-group, q-half

    unsigned EtB = (unsigned)(size_t)&Et[0][0];
    unsigned XtB = (unsigned)(size_t)&Xt[0][0];

    int q0 = qh * 2, q1 = q0 + 1;
    int d0 = ((lane & 3) + q0) & 3, d1 = ((lane & 3) + q1) & 3;
    int g0 = q0 * 16 + (lane >> 2), g1 = q1 * 16 + (lane >> 2);
    unsigned wb0 = (unsigned)((rg * 16 + (g0 >> 2)) * 128 + d0 * 32 + (g0 & 3) * 8);
    unsigned wb1 = (unsigned)((rg * 16 + (g1 >> 2)) * 128 + d1 * 32 + (g1 & 3) * 8);
    unsigned aB = EtB + (unsigned)(lhi * 4096 + wk * 512 + l15 * 8);
    unsigned bB = XtB + (unsigned)(lhi * 4096 + wi * 512 + l15 * 8);

    f32x4 vE0, vE1, vX0, vX1;
    f32x4 acc[4][4] = {};
    int nwin = (nEnd - nStart + 31) >> 5;

#define G1_LOAD(WIN)                                                        \
    {                                                                       \
        int nb_ = nStart + (WIN) * 32 + rg * 4;                             \
        int r0_ = nb_ + d0, r1_ = nb_ + d1;                                 \
        int a0_ = (r0_ < nEnd) ? r0_ : nStart;                              \
        int a1_ = (r1_ < nEnd) ? r1_ : nStart;                              \
        float m0_ = (r0_ < nEnd) ? 1.f : 0.f;                               \
        float m1_ = (r1_ < nEnd) ? 1.f : 0.f;                               \
        vE0 = *(const f32x4*)(E + (size_t)a0_ * 256 + g0 * 4) * m0_;        \
        vE1 = *(const f32x4*)(E + (size_t)a1_ * 256 + g1 * 4) * m1_;        \
        vX0 = *(const f32x4*)(X + (size_t)a0_ * 256 + g0 * 4) * m0_;        \
        vX1 = *(const f32x4*)(X + (size_t)a1_ * 256 + g1 * 4) * m1_;        \
    }

#define G1_WRITE(BUF)                                                       \
    {                                                                       \
        unsigned bo_ = (unsigned)(BUF) * 16384u;                            \
        *(u32x2*)((char*)Et + bo_ + wb0) =                                  \
            (u32x2){packbf2(vE0[0], vE0[1]), packbf2(vE0[2], vE0[3])};      \
        *(u32x2*)((char*)Et + bo_ + wb1) =                                  \
            (u32x2){packbf2(vE1[0], vE1[1]), packbf2(vE1[2], vE1[3])};      \
        *(u32x2*)((char*)Xt + bo_ + wb0) =                                  \
            (u32x2){packbf2(vX0[0], vX0[1]), packbf2(vX0[2], vX0[3])};      \
        *(u32x2*)((char*)Xt + bo_ + wb1) =                                  \
            (u32x2){packbf2(vX1[0], vX1[1]), packbf2(vX1[2], vX1[3])};      \
    }

#define G1_COMPUTE(BUF)                                                     \
    {                                                                       \
        unsigned bo_ = (unsigned)(BUF) * 16384u;                            \
        unsigned aB_ = aB + bo_, bB_ = bB + bo_;                            \
        s16x4 ta0[4], ta1[4], tb0[4], tb1[4];                               \
        _Pragma("unroll") for (int m = 0; m < 4; ++m) {                     \
            ta0[m] = trread(aB_ + m * 128);                                 \
            ta1[m] = trread2k(aB_ + m * 128);                               \
        }                                                                   \
        _Pragma("unroll") for (int c = 0; c < 4; ++c) {                     \
            tb0[c] = trread(bB_ + c * 128);                                 \
            tb1[c] = trread2k(bB_ + c * 128);                               \
        }                                                                   \
        LGKM0_FENCE();                                                      \
        s16x8 a[4], b[4];                                                   \
        _Pragma("unroll") for (int m = 0; m < 4; ++m) a[m] = cat44(ta0[m], ta1[m]); \
        _Pragma("unroll") for (int c = 0; c < 4; ++c) b[c] = cat44(tb0[c], tb1[c]); \
        _Pragma("unroll") for (int m = 0; m < 4; ++m)                       \
            _Pragma("unroll") for (int c = 0; c < 4; ++c)                   \
                acc[m][c] = __builtin_amdgcn_mfma_f32_16x16x32_bf16(        \
                    a[m], b[c], acc[m][c], 0, 0, 0);                        \
    }

    G1_LOAD(0);
    G1_WRITE(0);
    G1_LOAD(1);
    asm volatile("s_waitcnt lgkmcnt(0)" ::: "memory");
    __builtin_amdgcn_s_barrier();
    for (int win = 0; win < nwin; ++win) {
        int cur = win & 1;
        G1_COMPUTE(cur);
        if (win + 1 < nwin) G1_WRITE(cur ^ 1);
        if (win + 2 < nwin) G1_LOAD(win + 2);
        asm volatile("s_waitcnt lgkmcnt(0)" ::: "memory");
        __builtin_amdgcn_s_barrier();
    }
#undef G1_LOAD
#undef G1_WRITE
#undef G1_COMPUTE

    u16* dst = Pp + (size_t)chunk * 65536;
#pragma unroll
    for (int m = 0; m < 4; ++m) {
#pragma unroll
        for (int cf = 0; cf < 4; ++cf) {
            int ii = wi * 64 + cf * 16 + l15;
#pragma unroll
            for (int r = 0; r < 4; ++r) {
                int kk = wk * 64 + m * 16 + lhi * 4 + r;
                dst[kk * 256 + ii] = bfbits(acc[m][cf][r]);
            }
        }
    }
}

// ---------------- kernel 3: reduce bf16 partials -> Pb (bf16) ------------
__global__ void k_reduceP(const u32* __restrict__ Pp32,
                          u32* __restrict__ Pb32, int chunks) {
    int idx = blockIdx.x * 256 + threadIdx.x;   // 0..32767
    float s0 = 0.f, s1 = 0.f;
    for (int c = 0; c < chunks; ++c) {
        u32 vv = Pp32[(size_t)c * 32768 + idx];
        s0 += bf2f((u16)(vv & 0xffff));
        s1 += bf2f((u16)(vv >> 16));
    }
    Pb32[idx] = packbf2(s0, s1);
}

// ---------------- kernel 4: T[c] = P @ W_c^T (17 small GEMMs) ------------
__global__ __launch_bounds__(256, 4) void k_smallgemm(
    const u16* __restrict__ Pb, const float* __restrict__ c0,
    const float* __restrict__ cjr, const float* __restrict__ cji,
    float* __restrict__ T) {
    int c = blockIdx.x >> 3;
    int k0 = (blockIdx.x & 7) * 32;
    const float* W = (c == 0) ? c0 : (c <= 8 ? (cjr + (size_t)(c - 1) * 65536)
                                             : (cji + (size_t)(c - 9) * 65536));
    int t = threadIdx.x, lane = t & 63, wi = t >> 6;
    int l15 = lane & 15, lhi = lane >> 4;
    f32x4 acc[2][4] = {};
    for (int is = 0; is < 256; is += 32) {
        s16x8 a[2], b[4];
#pragma unroll
        for (int m = 0; m < 2; ++m)
            a[m] = *(const s16x8*)(Pb + (k0 + m * 16 + l15) * 256 + is + lhi * 8);
#pragma unroll
        for (int cf = 0; cf < 4; ++cf)
            b[cf] = cvt8(W + (size_t)(wi * 64 + cf * 16 + l15) * 256 + is + lhi * 8);
#pragma unroll
        for (int m = 0; m < 2; ++m)
#pragma unroll
            for (int cf = 0; cf < 4; ++cf)
                acc[m][cf] = __builtin_amdgcn_mfma_f32_16x16x32_bf16(
                    a[m], b[cf], acc[m][cf], 0, 0, 0);
    }
    float* dst = T + (size_t)c * 65536;
#pragma unroll
    for (int m = 0; m < 2; ++m) {
#pragma unroll
        for (int cf = 0; cf < 4; ++cf) {
            int oo = wi * 64 + cf * 16 + l15;
#pragma unroll
            for (int r = 0; r < 4; ++r) {
                int kk = k0 + m * 16 + lhi * 4 + r;
                dst[kk * 256 + oo] = acc[m][cf][r];
            }
        }
    }
}

// ---------------- kernel 5: combine T -> Qt bf16 (transposed) ------------
__global__ void k_combine(const float* __restrict__ T, const float* __restrict__ br,
                          const float* __restrict__ bi, u16* __restrict__ Qt) {
    int t = threadIdx.x;
    int k = blockIdx.x * 4 + (t >> 6);
    int o4 = (t & 63) * 4;
    f32x4 q = *(const f32x4*)(T + (size_t)k * 256 + o4);
#pragma unroll
    for (int j = 0; j < 8; ++j) {
        float brv = br[j * 256 + k], biv = bi[j * 256 + k];
        f32x4 tr = *(const f32x4*)(T + (size_t)(1 + j) * 65536 + k * 256 + o4);
        f32x4 ti = *(const f32x4*)(T + (size_t)(9 + j) * 65536 + k * 256 + o4);
        q += 2.0f * (brv * tr - biv * ti);
    }
#pragma unroll
    for (int e = 0; e < 4; ++e) Qt[(size_t)(o4 + e) * 256 + k] = bfbits(q[e]);
}

// ---------------- kernel 6: out = E @ Q ----------------------------------
// grid = 512 (2 blocks/CU); block 512 thr = 8 waves. Block tile 32n x 256o
// (full o -> E read once). Wave = 32n x 32o; Q-frags af[2][8] in regs.
// E staged f32 LINEAR via global_load_lds (1 KB row per wave-load), dbuf
// 2 x 32 KB; 16B-chunk swizzle s(r)=((r&7)+(r>>3))&7 applied on the GLOBAL
// source (G21) and on the LDS read -> bank-floor on both sides.
// T3/T4 loop: STAGE(t+1) -> compute(t)+stores -> vmcnt(4) -> barrier.
__global__ __launch_bounds__(512, 4) void k_gemm2(
    const float* __restrict__ E, const u16* __restrict__ Qt,
    float* __restrict__ out) {
    __shared__ alignas(16) float Ebuf[2][32 * 256];   // 2 x 32 KB

    int b = blockIdx.x;
    int tile0 = b * 6 + min(b, 53);      // 3125 = 512*6 + 53 tiles of 32 rows
    int nt = (b < 53) ? 7 : 6;

    int t = threadIdx.x, lane = t & 63, w = t >> 6;   // w = o-group 0..7
    int l15 = lane & 15, lhi = lane >> 4;
    int obase = w * 32;

    // Q fragments in registers: o = obase + m*16 + l15, k = ks*32 + lhi*8 ..+7
    s16x8 af[2][8];
#pragma unroll
    for (int m = 0; m < 2; ++m)
#pragma unroll
        for (int ks = 0; ks < 8; ++ks)
            af[m][ks] = *(const s16x8*)(Qt + (size_t)(obase + m * 16 + l15) * 256 +
                                        ks * 32 + lhi * 8);

#define G2_STAGE(TI, BUF)                                                   \
    {                                                                       \
        int gn_ = (tile0 + (TI)) * 32;                                      \
        _Pragma("unroll") for (int j = 0; j < 4; ++j) {                     \
            int r_ = w * 4 + j;                                             \
            int s_ = ((r_ & 7) + (r_ >> 3)) & 7;                            \
            gload16(E + (size_t)(gn_ + r_) * 256 + ((lane ^ s_) * 4),       \
                    (char*)Ebuf[BUF] + r_ * 1024);                          \
        }                                                                   \
    }

#define G2_TILE(TI, BUF)                                                    \
    {                                                                       \
        f32x4 acc[2][2] = {};                                               \
        const char* Eb_ = (const char*)Ebuf[BUF];                           \
        _Pragma("unroll") for (int ks = 0; ks < 8; ++ks) {                  \
            _Pragma("unroll") for (int q = 0; q < 2; ++q) {                 \
                int r_ = q * 16 + l15;                                      \
                int s_ = ((r_ & 7) + (r_ >> 3)) & 7;                        \
                int c0_ = ks * 8 + lhi * 2;                                 \
                f32x4 e0 = *(const f32x4*)(Eb_ + r_ * 1024 +                \
                                           ((c0_ ^ s_) * 16));              \
                f32x4 e1 = *(const f32x4*)(Eb_ + r_ * 1024 +                \
                                           (((c0_ + 1) ^ s_) * 16));        \
                s16x8 ef;                                                   \
                _Pragma("unroll") for (int e = 0; e < 4; ++e) {             \
                    ef[e] = (short)bfbits(e0[e]);                           \
                    ef[4 + e] = (short)bfbits(e1[e]);                       \
                }                                                           \
                _Pragma("unroll") for (int m = 0; m < 2; ++m)               \
                    acc[m][q] = __builtin_amdgcn_mfma_f32_16x16x32_bf16(    \
                        af[m][ks], ef, acc[m][q], 0, 0, 0);                 \
            }                                                               \
        }                                                                   \
        int gn_ = (tile0 + (TI)) * 32;                                      \
        _Pragma("unroll") for (int q = 0; q < 2; ++q)                       \
            _Pragma("unroll") for (int m = 0; m < 2; ++m)                   \
                *(f32x4*)(out + (size_t)(gn_ + q * 16 + l15) * 256 +        \
                          obase + m * 16 + lhi * 4) = acc[m][q];            \
    }

    G2_STAGE(0, 0);
    asm volatile("s_waitcnt vmcnt(0)" ::: "memory");
    __builtin_amdgcn_s_barrier();

    for (int i = 0; i < nt; ++i) {
        if (i + 1 < nt) G2_STAGE(i + 1, (i + 1) & 1);
        G2_TILE(i, i & 1);
        if (i + 1 < nt) {
            // queue/wave: [4 loads(t+1), 4 stores(t)] -> wait loads only
            asm volatile("s_waitcnt vmcnt(4)" ::: "memory");
            __builtin_amdgcn_s_barrier();
        }
    }
#undef G2_STAGE
#undef G2_TILE
}

// ---------------- host ---------------------------------------------------
extern "C" void kernel_launch(void* const* d_in, const int* in_sizes, int n_in,
                              void* d_out, int out_size, void* d_ws, size_t ws_size,
                              hipStream_t stream) {
    const float* x   = (const float*)d_in[0];
    const float* ev  = (const float*)d_in[1];
    const float* E   = (const float*)d_in[2];
    const float* hp  = (const float*)d_in[3];
    const float* ap  = (const float*)d_in[4];
    const float* c0  = (const float*)d_in[5];
    const float* cjr = (const float*)d_in[6];
    const float* cji = (const float*)d_in[7];
    float* out = (float*)d_out;

    char* ws = (char*)d_ws;
    float* br = (float*)(ws + 0);                 // 8 KB
    float* bi = (float*)(ws + 8192);              // 8 KB
    u16*   Pb = (u16*)(ws + 16384);               // 128 KB
    u16*   Qt = (u16*)(ws + 147456);              // 128 KB
    float* T  = (float*)(ws + 278528);            // 17*256 KB -> 4.73 MB

    // P partials (bf16, 256 x 128 KB = 33.5 MB) live in d_out scratch;
    // consumed by reduceP before gemm2 overwrites d_out (stream-ordered).
    u16* Pp = (u16*)d_out;
    const int chunks = 256;
    const int NB = (NTOT + chunks - 1) / chunks;  // 392

    k_weights<<<1, 256, 0, stream>>>(ev, hp, ap, br, bi);
    k_gemm1<<<chunks, 1024, 0, stream>>>(E, x, Pp, NB);
    k_reduceP<<<128, 256, 0, stream>>>((const u32*)Pp, (u32*)Pb, chunks);
    k_smallgemm<<<17 * 8, 256, 0, stream>>>(Pb, c0, cjr, cji, T);
    k_combine<<<64, 256, 0, stream>>>(T, br, bi, Qt);
    k_gemm2<<<512, 512, 0, stream>>>(E, Qt, out);
}